// Round 4
// baseline (483.143 us; speedup 1.0000x reference)
//
#include <hip/hip_runtime.h>
#include <hip/hip_bf16.h>
#include <stdint.h>

typedef __attribute__((ext_vector_type(8))) short short8;
typedef __attribute__((ext_vector_type(4))) float f32x4;

#define HEADS 16
#define HDIM  128
#define BB    2
#define TT    2048
#define DMODEL 2048
#define INNER 2048
#define E3    6144
#define NTOK  (BB*TT)

__device__ inline void store1(__hip_bfloat16* p, float v) { *p = __float2bfloat16(v); }
__device__ inline void store1(float* p, float v)          { *p = v; }

// async global->LDS, 16 B per lane. LDS dest is wave-uniform base + lane*16.
__device__ inline void gl_lds16(const __hip_bfloat16* g, __hip_bfloat16* l) {
  __builtin_amdgcn_global_load_lds(
      (const __attribute__((address_space(1))) void*)g,
      (__attribute__((address_space(3))) void*)l, 16, 0, 0);
}

// ---------------------------------------------------------------------------
// fp32 -> bf16 pack, 8 elems/thread. n must be a multiple of 8.
// ---------------------------------------------------------------------------
__global__ __launch_bounds__(256)
void cvt_bf16(const float* __restrict__ in, __hip_bfloat16* __restrict__ out, int n)
{
  int i = (blockIdx.x * 256 + threadIdx.x) * 8;
  if (i >= n) return;
  float4 a = *(const float4*)(in + i);
  float4 b = *(const float4*)(in + i + 4);
  short8 r;
  __hip_bfloat16 h;
  h = __float2bfloat16(a.x); r[0] = *(short*)&h;
  h = __float2bfloat16(a.y); r[1] = *(short*)&h;
  h = __float2bfloat16(a.z); r[2] = *(short*)&h;
  h = __float2bfloat16(a.w); r[3] = *(short*)&h;
  h = __float2bfloat16(b.x); r[4] = *(short*)&h;
  h = __float2bfloat16(b.y); r[5] = *(short*)&h;
  h = __float2bfloat16(b.z); r[6] = *(short*)&h;
  h = __float2bfloat16(b.w); r[7] = *(short*)&h;
  *(short8*)(out + i) = r;
}

// ---------------------------------------------------------------------------
// m97-style GEMM: C[M][N] = sum_k A[m][k]*B[n][k], bf16 in, fp32 acc.
// 128x128 tile, 4 waves (2x2), 4x4 of 16x16x32 MFMA per wave.
// Staging via global_load_lds width=16 into unpadded row-major 128x32 tiles.
// ---------------------------------------------------------------------------
template<typename TC>
__global__ __launch_bounds__(256, 2)
void gemm_lds(const __hip_bfloat16* __restrict__ A,
              const __hip_bfloat16* __restrict__ B,
              TC* __restrict__ C,
              int M, int N, int K)
{
  __shared__ __hip_bfloat16 sA[128*32];
  __shared__ __hip_bfloat16 sB[128*32];
  const int tid  = threadIdx.x;
  const int lane = tid & 63;
  const int wv   = tid >> 6;
  const int lm   = lane & 15;
  const int quad = lane >> 4;
  const int wm   = (wv >> 1) * 64;
  const int wn   = (wv & 1) * 64;
  const int bm   = blockIdx.y * 128;
  const int bn   = blockIdx.x * 128;

  f32x4 acc[4][4];
  #pragma unroll
  for (int i=0;i<4;i++)
    #pragma unroll
    for (int j=0;j<4;j++) acc[i][j] = (f32x4){0.f,0.f,0.f,0.f};

  const int srow = wv*32 + (lane >> 2);
  const int scol = (lane & 3) * 8;
  const __hip_bfloat16* gA0 = A + (size_t)(bm + srow)*K + scol;
  const __hip_bfloat16* gA1 = gA0 + (size_t)16*K;
  const __hip_bfloat16* gB0 = B + (size_t)(bn + srow)*K + scol;
  const __hip_bfloat16* gB1 = gB0 + (size_t)16*K;
  __hip_bfloat16* lA0 = sA + wv*1024;   // wave-uniform dest
  __hip_bfloat16* lA1 = lA0 + 512;
  __hip_bfloat16* lB0 = sB + wv*1024;
  __hip_bfloat16* lB1 = lB0 + 512;

  for (int k0 = 0; k0 < K; k0 += 32) {
    __syncthreads();
    gl_lds16(gA0, lA0);
    gl_lds16(gA1, lA1);
    gl_lds16(gB0, lB0);
    gl_lds16(gB1, lB1);
    gA0 += 32; gA1 += 32; gB0 += 32; gB1 += 32;
    __syncthreads();
    short8 af[4], bf[4];
    #pragma unroll
    for (int t=0;t<4;t++)
      af[t] = *(const short8*)(sA + (wm + t*16 + lm)*32 + quad*8);
    #pragma unroll
    for (int t=0;t<4;t++)
      bf[t] = *(const short8*)(sB + (wn + t*16 + lm)*32 + quad*8);
    #pragma unroll
    for (int i=0;i<4;i++)
      #pragma unroll
      for (int j=0;j<4;j++)
        acc[i][j] = __builtin_amdgcn_mfma_f32_16x16x32_bf16(af[i], bf[j], acc[i][j], 0,0,0);
  }

  const int row0 = bm + wm + quad*4;
  const int col0 = bn + wn + lm;
  #pragma unroll
  for (int i=0;i<4;i++)
    #pragma unroll
    for (int j=0;j<4;j++)
      #pragma unroll
      for (int r=0;r<4;r++)
        store1(C + (size_t)(row0 + i*16 + r)*N + col0 + j*16, acc[i][j][r]);
}

// ---------------------------------------------------------------------------
// RoPE + split + head reshape. qkv[B][T][3*INNER] (bf16) -> Qh,Kh (B,H,T,D)
// with RoPE, Vt (B,H,D,T) transposed via LDS tile.
// Q is pre-multiplied by (1/sqrt(D))*log2(e) so flash can use exp2 directly.
// ---------------------------------------------------------------------------
__global__ __launch_bounds__(256)
void rope_split(const __hip_bfloat16* __restrict__ qkv,
                __hip_bfloat16* __restrict__ Qh,
                __hip_bfloat16* __restrict__ Kh,
                __hip_bfloat16* __restrict__ Vt)
{
  const int tid = threadIdx.x;
  const int t0  = blockIdx.x * 32;
  const int bh  = blockIdx.y;
  const int b   = bh >> 4;
  const int h   = bh & 15;
  __shared__ __hip_bfloat16 sv[128][33];
  const float SC = 0.08838834764831845f * 1.4426950408889634f;  // scale*log2(e)

  #pragma unroll
  for (int it=0; it<8; ++it) {
    int idx = it*256 + tid;
    int tl  = idx >> 6;     // 0..31
    int d2  = idx & 63;     // 0..63 (pair index)
    int t   = t0 + tl;
    size_t base = ((size_t)b*TT + t)*E3 + (size_t)h*HDIM;
    float q1 = __bfloat162float(qkv[base + d2]);
    float q2 = __bfloat162float(qkv[base + d2 + 64]);
    float k1 = __bfloat162float(qkv[base + INNER + d2]);
    float k2 = __bfloat162float(qkv[base + INNER + d2 + 64]);
    float inv = powf(10000.f, -(float)d2 * (1.f/64.f));
    float ang = (float)t * inv;
    float c = cosf(ang), s = sinf(ang);
    size_t qo = ((size_t)bh*TT + t)*HDIM;
    Qh[qo + d2]      = __float2bfloat16((q1*c - q2*s)*SC);
    Qh[qo + d2 + 64] = __float2bfloat16((q2*c + q1*s)*SC);
    Kh[qo + d2]      = __float2bfloat16(k1*c - k2*s);
    Kh[qo + d2 + 64] = __float2bfloat16(k2*c + k1*s);
    sv[d2][tl]      = qkv[base + 2*INNER + d2];
    sv[d2+64][tl]   = qkv[base + 2*INNER + d2 + 64];
  }
  __syncthreads();
  #pragma unroll
  for (int it=0; it<16; ++it) {
    int idx = it*256 + tid;
    int d   = idx >> 5;     // 0..127
    int tl  = idx & 31;
    Vt[((size_t)bh*HDIM + d)*TT + t0 + tl] = sv[d][tl];
  }
}

// ---------------------------------------------------------------------------
// Causal flash attention, paired q-tiles for uniform work.
// Block handles q-tiles jA and 31-jA of one (b,h); K/V staged once per kv tile
// and consumed by both. Fixed-max softmax: p = 2^(s' - FML2), s' = QK with Q
// pre-scaled by scale*log2e. l reduction deferred to after the kv loop.
// Register double-buffer on K/V staging hides global latency under compute.
// ---------------------------------------------------------------------------
__global__ __launch_bounds__(256, 2)
void flash_attn(const __hip_bfloat16* __restrict__ Qh,
                const __hip_bfloat16* __restrict__ Kh,
                const __hip_bfloat16* __restrict__ Vt,
                __hip_bfloat16* __restrict__ Out)
{
  const int tid  = threadIdx.x;
  const int lane = tid & 63;
  const int wv   = tid >> 6;
  const int lm   = lane & 15;
  const int quad = lane >> 4;
  const int jA   = blockIdx.x;            // 0..15
  const int qA   = jA * 64;
  const int qB   = (31 - jA) * 64;
  const int bh   = blockIdx.y;
  const int b    = bh >> 4;
  const int h    = bh & 15;

  __shared__ __hip_bfloat16 sK[64*136];    // [kj][d]  stride 136
  __shared__ __hip_bfloat16 sV[128*72];    // [d][kj]  stride 72
  __shared__ __hip_bfloat16 sP[4][16*72];  // per-wave P [qrow][kj]

  short8 aqA[4], aqB[4];
  {
    const __hip_bfloat16* qpA = Qh + ((size_t)bh*TT + qA + wv*16 + lm)*HDIM + quad*8;
    const __hip_bfloat16* qpB = Qh + ((size_t)bh*TT + qB + wv*16 + lm)*HDIM + quad*8;
    #pragma unroll
    for (int kd=0;kd<4;kd++) { aqA[kd] = *(const short8*)(qpA + kd*32);
                               aqB[kd] = *(const short8*)(qpB + kd*32); }
  }

  float l_pA[4] = {0,0,0,0}, l_pB[4] = {0,0,0,0};
  f32x4 accA[8], accB[8];
  #pragma unroll
  for (int i=0;i<8;i++) { accA[i] = (f32x4){0.f,0.f,0.f,0.f};
                          accB[i] = (f32x4){0.f,0.f,0.f,0.f}; }

  const float FML2 = 8.0f * 1.4426950408889634f;  // fixed max, log2 domain

  // staging maps: per thread 4 K-chunks (rows it*16+rk0, fixed col ck) and
  // 4 V-chunks (rows it*32+dv0, fixed col cv)
  const int rk0 = tid >> 4;
  const int ck  = (tid & 15) * 8;
  const int dv0 = tid >> 3;
  const int cv  = (tid & 7) * 8;
  const __hip_bfloat16* Kp = Kh + (size_t)bh*TT*HDIM + (size_t)rk0*HDIM + ck;
  const __hip_bfloat16* Vp = Vt + (size_t)bh*HDIM*TT + (size_t)dv0*TT + cv;

  short8 pk[4], pv[4];
  #pragma unroll
  for (int it=0;it<4;++it) {
    pk[it] = *(const short8*)(Kp + (size_t)it*16*HDIM);
    pv[it] = *(const short8*)(Vp + (size_t)it*32*TT);
  }
  Kp += (size_t)64*HDIM; Vp += 64;

  auto do_tile = [&](const short8* aq, int q0t, f32x4* acc_o, float* l_p, int kv0) {
    f32x4 accs[4];
    #pragma unroll
    for (int nt=0;nt<4;nt++) accs[nt] = (f32x4){0.f,0.f,0.f,0.f};
    #pragma unroll
    for (int kd=0;kd<4;kd++)
      #pragma unroll
      for (int nt=0;nt<4;nt++) {
        short8 bk = *(const short8*)(&sK[(nt*16 + lm)*136 + kd*32 + quad*8]);
        accs[nt] = __builtin_amdgcn_mfma_f32_16x16x32_bf16(aq[kd], bk, accs[nt], 0,0,0);
      }
    const int rowb = q0t + wv*16 + quad*4;
    const bool diag = (kv0 == q0t);
    #pragma unroll
    for (int nt=0;nt<4;nt++)
      #pragma unroll
      for (int r=0;r<4;r++) {
        float p = exp2f(accs[nt][r] - FML2);
        if (diag && (kv0 + nt*16 + lm > rowb + r)) p = 0.f;
        l_p[r] += p;
        sP[wv][(quad*4 + r)*72 + nt*16 + lm] = __float2bfloat16(p);
      }
    #pragma unroll
    for (int kd2=0;kd2<2;kd2++) {
      short8 ap = *(const short8*)(&sP[wv][lm*72 + kd2*32 + quad*8]);
      #pragma unroll
      for (int nt2=0;nt2<8;nt2++) {
        short8 bvv = *(const short8*)(&sV[(nt2*16 + lm)*72 + kd2*32 + quad*8]);
        acc_o[nt2] = __builtin_amdgcn_mfma_f32_16x16x32_bf16(ap, bvv, acc_o[nt2], 0,0,0);
      }
    }
  };

  for (int kv0 = 0; kv0 <= qB; kv0 += 64) {
    __syncthreads();                 // all waves done reading previous tile
    #pragma unroll
    for (int it=0;it<4;++it) {
      *(short8*)(&sK[(it*16 + rk0)*136 + ck]) = pk[it];
      *(short8*)(&sV[(it*32 + dv0)*72 + cv])  = pv[it];
    }
    if (kv0 + 64 <= qB) {            // prefetch next tile into regs
      #pragma unroll
      for (int it=0;it<4;++it) {
        pk[it] = *(const short8*)(Kp + (size_t)it*16*HDIM);
        pv[it] = *(const short8*)(Vp + (size_t)it*32*TT);
      }
      Kp += (size_t)64*HDIM; Vp += 64;
    }
    __syncthreads();                 // tile visible

    do_tile(aqB, qB, accB, l_pB, kv0);
    if (kv0 <= qA)
      do_tile(aqA, qA, accA, l_pA, kv0);
  }

  // deferred cross-lane l reduction (within 16-lane groups)
  #pragma unroll
  for (int off=1; off<16; off<<=1)
    #pragma unroll
    for (int r=0;r<4;r++) {
      l_pA[r] += __shfl_xor(l_pA[r], off);
      l_pB[r] += __shfl_xor(l_pB[r], off);
    }

  #pragma unroll
  for (int r=0;r<4;r++) { l_pA[r] = 1.f / l_pA[r]; l_pB[r] = 1.f / l_pB[r]; }
  #pragma unroll
  for (int nt2=0;nt2<8;nt2++)
    #pragma unroll
    for (int r=0;r<4;r++) {
      int tA = qA + wv*16 + quad*4 + r;
      int tB = qB + wv*16 + quad*4 + r;
      size_t col = (size_t)h*HDIM + nt2*16 + lm;
      Out[((size_t)b*TT + tA)*INNER + col] = __float2bfloat16(accA[nt2][r] * l_pA[r]);
      Out[((size_t)b*TT + tB)*INNER + col] = __float2bfloat16(accB[nt2][r] * l_pB[r]);
    }
}

// ---------------------------------------------------------------------------
extern "C" void kernel_launch(void* const* d_in, const int* in_sizes, int n_in,
                              void* d_out, int out_size, void* d_ws, size_t ws_size,
                              hipStream_t stream)
{
  (void)in_sizes; (void)n_in; (void)out_size; (void)ws_size;
  const float* x     = (const float*)d_in[0];   // fp32 per reference
  const float* Wqkv  = (const float*)d_in[1];
  const float* Wproj = (const float*)d_in[2];
  float* out = (float*)d_out;                   // fp32 output

  // Workspace layout (100.66 MB):
  //  slot0 [0, 50.33 MB): qkv (bf16)  -> later attn_out [0,16.78) + Wprojb [16.78,25.17)
  //  slot1 [50.33, 100.66): xb[0,16.78)+Wqkvb[16.78,41.94) -> later Qh/Kh/Vt
  char* ws = (char*)d_ws;
  __hip_bfloat16* qkv   = (__hip_bfloat16*)ws;
  __hip_bfloat16* attn_out = qkv;
  __hip_bfloat16* Wprojb = (__hip_bfloat16*)(ws + (size_t)NTOK*INNER*2);
  char* slot1 = ws + (size_t)NTOK*E3*2;
  __hip_bfloat16* xb     = (__hip_bfloat16*)slot1;
  __hip_bfloat16* Wqkvb  = (__hip_bfloat16*)(slot1 + (size_t)NTOK*DMODEL*2);
  __hip_bfloat16* Qh     = (__hip_bfloat16*)slot1;
  __hip_bfloat16* Kh     = (__hip_bfloat16*)(slot1 + (size_t)BB*HEADS*TT*HDIM*2);
  __hip_bfloat16* Vt     = (__hip_bfloat16*)(slot1 + (size_t)2*BB*HEADS*TT*HDIM*2);

  const int n_x = NTOK*DMODEL, n_wqkv = E3*DMODEL, n_wproj = DMODEL*INNER;
  cvt_bf16<<<dim3(n_x/(256*8)),    dim3(256), 0, stream>>>(x,    xb,    n_x);
  cvt_bf16<<<dim3(n_wqkv/(256*8)), dim3(256), 0, stream>>>(Wqkv, Wqkvb, n_wqkv);

  gemm_lds<__hip_bfloat16>
    <<<dim3(E3/128, NTOK/128), dim3(256), 0, stream>>>(xb, Wqkvb, qkv, NTOK, E3, DMODEL);

  rope_split<<<dim3(TT/32, BB*HEADS), dim3(256), 0, stream>>>(qkv, Qh, Kh, Vt);

  // xb/Wqkvb dead; Qh/Kh/Vt live. Convert Wproj into dead tail of slot0.
  cvt_bf16<<<dim3(n_wproj/(256*8)), dim3(256), 0, stream>>>(Wproj, Wprojb, n_wproj);

  flash_attn<<<dim3(TT/128, BB*HEADS), dim3(256), 0, stream>>>(Qh, Kh, Vt, attn_out);

  gemm_lds<float>
    <<<dim3(INNER/128, NTOK/128), dim3(256), 0, stream>>>(attn_out, Wprojb, out, NTOK, INNER, DMODEL);
}

// Round 5
// 411.764 us; speedup vs baseline: 1.1734x; 1.1734x over previous
//
#include <hip/hip_runtime.h>
#include <hip/hip_bf16.h>
#include <stdint.h>

typedef __attribute__((ext_vector_type(8))) short short8;
typedef __attribute__((ext_vector_type(4))) float f32x4;

#define HEADS 16
#define HDIM  128
#define BB    2
#define TT    2048
#define DMODEL 2048
#define INNER 2048
#define E3    6144
#define NTOK  (BB*TT)

__device__ inline void store1(__hip_bfloat16* p, float v) { *p = __float2bfloat16(v); }
__device__ inline void store1(float* p, float v)          { *p = v; }

// async global->LDS, 16 B per lane. LDS dest is wave-uniform base + lane*16.
__device__ inline void gl_lds16(const __hip_bfloat16* g, __hip_bfloat16* l) {
  __builtin_amdgcn_global_load_lds(
      (const __attribute__((address_space(1))) void*)g,
      (__attribute__((address_space(3))) void*)l, 16, 0, 0);
}

// ---------------------------------------------------------------------------
// fp32 -> bf16 pack, 8 elems/thread. n must be a multiple of 8.
// ---------------------------------------------------------------------------
__global__ __launch_bounds__(256)
void cvt_bf16(const float* __restrict__ in, __hip_bfloat16* __restrict__ out, int n)
{
  int i = (blockIdx.x * 256 + threadIdx.x) * 8;
  if (i >= n) return;
  float4 a = *(const float4*)(in + i);
  float4 b = *(const float4*)(in + i + 4);
  short8 r;
  __hip_bfloat16 h;
  h = __float2bfloat16(a.x); r[0] = *(short*)&h;
  h = __float2bfloat16(a.y); r[1] = *(short*)&h;
  h = __float2bfloat16(a.z); r[2] = *(short*)&h;
  h = __float2bfloat16(a.w); r[3] = *(short*)&h;
  h = __float2bfloat16(b.x); r[4] = *(short*)&h;
  h = __float2bfloat16(b.y); r[5] = *(short*)&h;
  h = __float2bfloat16(b.z); r[6] = *(short*)&h;
  h = __float2bfloat16(b.w); r[7] = *(short*)&h;
  *(short8*)(out + i) = r;
}

// ---------------------------------------------------------------------------
// m97-style GEMM: C[M][N] = sum_k A[m][k]*B[n][k], bf16 in, fp32 acc.
// 128x128 tile, 4 waves (2x2), 4x4 of 16x16x32 MFMA per wave.
// Staging via global_load_lds width=16 into unpadded row-major 128x32 tiles.
// ---------------------------------------------------------------------------
template<typename TC>
__global__ __launch_bounds__(256, 2)
void gemm_lds(const __hip_bfloat16* __restrict__ A,
              const __hip_bfloat16* __restrict__ B,
              TC* __restrict__ C,
              int M, int N, int K)
{
  __shared__ __hip_bfloat16 sA[128*32];
  __shared__ __hip_bfloat16 sB[128*32];
  const int tid  = threadIdx.x;
  const int lane = tid & 63;
  const int wv   = tid >> 6;
  const int lm   = lane & 15;
  const int quad = lane >> 4;
  const int wm   = (wv >> 1) * 64;
  const int wn   = (wv & 1) * 64;
  const int bm   = blockIdx.y * 128;
  const int bn   = blockIdx.x * 128;

  f32x4 acc[4][4];
  #pragma unroll
  for (int i=0;i<4;i++)
    #pragma unroll
    for (int j=0;j<4;j++) acc[i][j] = (f32x4){0.f,0.f,0.f,0.f};

  const int srow = wv*32 + (lane >> 2);
  const int scol = (lane & 3) * 8;
  const __hip_bfloat16* gA0 = A + (size_t)(bm + srow)*K + scol;
  const __hip_bfloat16* gA1 = gA0 + (size_t)16*K;
  const __hip_bfloat16* gB0 = B + (size_t)(bn + srow)*K + scol;
  const __hip_bfloat16* gB1 = gB0 + (size_t)16*K;
  __hip_bfloat16* lA0 = sA + wv*1024;   // wave-uniform dest
  __hip_bfloat16* lA1 = lA0 + 512;
  __hip_bfloat16* lB0 = sB + wv*1024;
  __hip_bfloat16* lB1 = lB0 + 512;

  for (int k0 = 0; k0 < K; k0 += 32) {
    __syncthreads();
    gl_lds16(gA0, lA0);
    gl_lds16(gA1, lA1);
    gl_lds16(gB0, lB0);
    gl_lds16(gB1, lB1);
    gA0 += 32; gA1 += 32; gB0 += 32; gB1 += 32;
    __syncthreads();
    short8 af[4], bf[4];
    #pragma unroll
    for (int t=0;t<4;t++)
      af[t] = *(const short8*)(sA + (wm + t*16 + lm)*32 + quad*8);
    #pragma unroll
    for (int t=0;t<4;t++)
      bf[t] = *(const short8*)(sB + (wn + t*16 + lm)*32 + quad*8);
    #pragma unroll
    for (int i=0;i<4;i++)
      #pragma unroll
      for (int j=0;j<4;j++)
        acc[i][j] = __builtin_amdgcn_mfma_f32_16x16x32_bf16(af[i], bf[j], acc[i][j], 0,0,0);
  }

  const int row0 = bm + wm + quad*4;
  const int col0 = bn + wn + lm;
  #pragma unroll
  for (int i=0;i<4;i++)
    #pragma unroll
    for (int j=0;j<4;j++)
      #pragma unroll
      for (int r=0;r<4;r++)
        store1(C + (size_t)(row0 + i*16 + r)*N + col0 + j*16, acc[i][j][r]);
}

// ---------------------------------------------------------------------------
// RoPE + split + head reshape. qkv[B][T][3*INNER] (bf16) -> Qh,Kh (B,H,T,D)
// with RoPE, Vt (B,H,D,T) transposed via LDS tile.
// Q is pre-multiplied by (1/sqrt(D))*log2(e) so flash can use exp2 directly.
// ---------------------------------------------------------------------------
__global__ __launch_bounds__(256)
void rope_split(const __hip_bfloat16* __restrict__ qkv,
                __hip_bfloat16* __restrict__ Qh,
                __hip_bfloat16* __restrict__ Kh,
                __hip_bfloat16* __restrict__ Vt)
{
  const int tid = threadIdx.x;
  const int t0  = blockIdx.x * 32;
  const int bh  = blockIdx.y;
  const int b   = bh >> 4;
  const int h   = bh & 15;
  __shared__ __hip_bfloat16 sv[128][33];
  const float SC = 0.08838834764831845f * 1.4426950408889634f;  // scale*log2(e)

  #pragma unroll
  for (int it=0; it<8; ++it) {
    int idx = it*256 + tid;
    int tl  = idx >> 6;     // 0..31
    int d2  = idx & 63;     // 0..63 (pair index)
    int t   = t0 + tl;
    size_t base = ((size_t)b*TT + t)*E3 + (size_t)h*HDIM;
    float q1 = __bfloat162float(qkv[base + d2]);
    float q2 = __bfloat162float(qkv[base + d2 + 64]);
    float k1 = __bfloat162float(qkv[base + INNER + d2]);
    float k2 = __bfloat162float(qkv[base + INNER + d2 + 64]);
    float inv = powf(10000.f, -(float)d2 * (1.f/64.f));
    float ang = (float)t * inv;
    float c = cosf(ang), s = sinf(ang);
    size_t qo = ((size_t)bh*TT + t)*HDIM;
    Qh[qo + d2]      = __float2bfloat16((q1*c - q2*s)*SC);
    Qh[qo + d2 + 64] = __float2bfloat16((q2*c + q1*s)*SC);
    Kh[qo + d2]      = __float2bfloat16(k1*c - k2*s);
    Kh[qo + d2 + 64] = __float2bfloat16(k2*c + k1*s);
    sv[d2][tl]      = qkv[base + 2*INNER + d2];
    sv[d2+64][tl]   = qkv[base + 2*INNER + d2 + 64];
  }
  __syncthreads();
  #pragma unroll
  for (int it=0; it<16; ++it) {
    int idx = it*256 + tid;
    int d   = idx >> 5;     // 0..127
    int tl  = idx & 31;
    Vt[((size_t)bh*HDIM + d)*TT + t0 + tl] = sv[d][tl];
  }
}

// ---------------------------------------------------------------------------
// Causal flash attention, paired q-tiles processed SEQUENTIALLY for uniform
// per-block work with single-tile register state (R4's interleaved version
// spilled: 128 VGPR cap, 332 MB scratch writes).
// Block = q-tiles jA and 31-jA of one (b,h), one after the other.
// Fixed-max softmax p = 2^(s' - FML2), Q pre-scaled by scale*log2e.
// Register prefetch of next K/V tile issues global loads before the barrier.
// ---------------------------------------------------------------------------
__global__ __launch_bounds__(256, 2)
void flash_attn(const __hip_bfloat16* __restrict__ Qh,
                const __hip_bfloat16* __restrict__ Kh,
                const __hip_bfloat16* __restrict__ Vt,
                __hip_bfloat16* __restrict__ Out)
{
  const int tid  = threadIdx.x;
  const int lane = tid & 63;
  const int wv   = tid >> 6;
  const int lm   = lane & 15;
  const int quad = lane >> 4;
  const int jA   = blockIdx.x;            // 0..15
  const int bh   = blockIdx.y;
  const int b    = bh >> 4;
  const int h    = bh & 15;

  __shared__ __hip_bfloat16 sK[64*136];    // [kj][d]  stride 136
  __shared__ __hip_bfloat16 sV[128*72];    // [d][kj]  stride 72
  __shared__ __hip_bfloat16 sP[4][16*72];  // per-wave P [qrow][kj]

  const float FML2 = 8.0f * 1.4426950408889634f;  // fixed max, log2 domain

  // staging maps
  const int rk0 = tid >> 4;
  const int ck  = (tid & 15) * 8;
  const int dv0 = tid >> 3;
  const int cv  = (tid & 7) * 8;
  const __hip_bfloat16* KpBase = Kh + (size_t)bh*TT*HDIM + (size_t)rk0*HDIM + ck;
  const __hip_bfloat16* VpBase = Vt + (size_t)bh*HDIM*TT + (size_t)dv0*TT + cv;

  #pragma unroll
  for (int pass = 0; pass < 2; ++pass) {
    const int q0 = (pass == 0 ? jA : 31 - jA) * 64;

    short8 aq[4];
    {
      const __hip_bfloat16* qp = Qh + ((size_t)bh*TT + q0 + wv*16 + lm)*HDIM + quad*8;
      #pragma unroll
      for (int kd=0;kd<4;kd++) aq[kd] = *(const short8*)(qp + kd*32);
    }

    float l_p[4] = {0,0,0,0};
    f32x4 acc_o[8];
    #pragma unroll
    for (int i=0;i<8;i++) acc_o[i] = (f32x4){0.f,0.f,0.f,0.f};

    const __hip_bfloat16* Kp = KpBase;
    const __hip_bfloat16* Vp = VpBase;
    short8 pk[4], pv[4];
    #pragma unroll
    for (int it=0;it<4;++it) {
      pk[it] = *(const short8*)(Kp + (size_t)it*16*HDIM);
      pv[it] = *(const short8*)(Vp + (size_t)it*32*TT);
    }
    Kp += (size_t)64*HDIM; Vp += 64;

    for (int kv0 = 0; kv0 <= q0; kv0 += 64) {
      __syncthreads();               // all waves done reading previous tile
      #pragma unroll
      for (int it=0;it<4;++it) {
        *(short8*)(&sK[(it*16 + rk0)*136 + ck]) = pk[it];
        *(short8*)(&sV[(it*32 + dv0)*72 + cv])  = pv[it];
      }
      if (kv0 + 64 <= q0) {          // prefetch next tile into regs
        #pragma unroll
        for (int it=0;it<4;++it) {
          pk[it] = *(const short8*)(Kp + (size_t)it*16*HDIM);
          pv[it] = *(const short8*)(Vp + (size_t)it*32*TT);
        }
        Kp += (size_t)64*HDIM; Vp += 64;
      }
      __syncthreads();               // tile visible

      // S = Q K^T : wave's 16 rows x 64 cols
      f32x4 accs[4];
      #pragma unroll
      for (int nt=0;nt<4;nt++) accs[nt] = (f32x4){0.f,0.f,0.f,0.f};
      #pragma unroll
      for (int kd=0;kd<4;kd++)
        #pragma unroll
        for (int nt=0;nt<4;nt++) {
          short8 bk = *(const short8*)(&sK[(nt*16 + lm)*136 + kd*32 + quad*8]);
          accs[nt] = __builtin_amdgcn_mfma_f32_16x16x32_bf16(aq[kd], bk, accs[nt], 0,0,0);
        }

      // p = 2^(s' - FML2); causal zeroing on the diagonal tile
      const int rowb = q0 + wv*16 + quad*4;
      const bool diag = (kv0 == q0);
      #pragma unroll
      for (int nt=0;nt<4;nt++)
        #pragma unroll
        for (int r=0;r<4;r++) {
          float p = exp2f(accs[nt][r] - FML2);
          if (diag && (kv0 + nt*16 + lm > rowb + r)) p = 0.f;
          l_p[r] += p;
          sP[wv][(quad*4 + r)*72 + nt*16 + lm] = __float2bfloat16(p);
        }

      // O += P V  (sP is wave-private)
      #pragma unroll
      for (int kd2=0;kd2<2;kd2++) {
        short8 ap = *(const short8*)(&sP[wv][lm*72 + kd2*32 + quad*8]);
        #pragma unroll
        for (int nt2=0;nt2<8;nt2++) {
          short8 bvv = *(const short8*)(&sV[(nt2*16 + lm)*72 + kd2*32 + quad*8]);
          acc_o[nt2] = __builtin_amdgcn_mfma_f32_16x16x32_bf16(ap, bvv, acc_o[nt2], 0,0,0);
        }
      }
    }

    // deferred cross-lane l reduction (within 16-lane groups)
    #pragma unroll
    for (int off=1; off<16; off<<=1)
      #pragma unroll
      for (int r=0;r<4;r++) l_p[r] += __shfl_xor(l_p[r], off);
    #pragma unroll
    for (int r=0;r<4;r++) l_p[r] = 1.f / l_p[r];

    #pragma unroll
    for (int nt2=0;nt2<8;nt2++)
      #pragma unroll
      for (int r=0;r<4;r++) {
        int t = q0 + wv*16 + quad*4 + r;
        Out[((size_t)b*TT + t)*INNER + (size_t)h*HDIM + nt2*16 + lm] =
          __float2bfloat16(acc_o[nt2][r] * l_p[r]);
      }
  }
}

// ---------------------------------------------------------------------------
extern "C" void kernel_launch(void* const* d_in, const int* in_sizes, int n_in,
                              void* d_out, int out_size, void* d_ws, size_t ws_size,
                              hipStream_t stream)
{
  (void)in_sizes; (void)n_in; (void)out_size; (void)ws_size;
  const float* x     = (const float*)d_in[0];   // fp32 per reference
  const float* Wqkv  = (const float*)d_in[1];
  const float* Wproj = (const float*)d_in[2];
  float* out = (float*)d_out;                   // fp32 output

  // Workspace layout (100.66 MB):
  //  slot0 [0, 50.33 MB): qkv (bf16)  -> later attn_out [0,16.78) + Wprojb [16.78,25.17)
  //  slot1 [50.33, 100.66): xb[0,16.78)+Wqkvb[16.78,41.94) -> later Qh/Kh/Vt
  char* ws = (char*)d_ws;
  __hip_bfloat16* qkv   = (__hip_bfloat16*)ws;
  __hip_bfloat16* attn_out = qkv;
  __hip_bfloat16* Wprojb = (__hip_bfloat16*)(ws + (size_t)NTOK*INNER*2);
  char* slot1 = ws + (size_t)NTOK*E3*2;
  __hip_bfloat16* xb     = (__hip_bfloat16*)slot1;
  __hip_bfloat16* Wqkvb  = (__hip_bfloat16*)(slot1 + (size_t)NTOK*DMODEL*2);
  __hip_bfloat16* Qh     = (__hip_bfloat16*)slot1;
  __hip_bfloat16* Kh     = (__hip_bfloat16*)(slot1 + (size_t)BB*HEADS*TT*HDIM*2);
  __hip_bfloat16* Vt     = (__hip_bfloat16*)(slot1 + (size_t)2*BB*HEADS*TT*HDIM*2);

  const int n_x = NTOK*DMODEL, n_wqkv = E3*DMODEL, n_wproj = DMODEL*INNER;
  cvt_bf16<<<dim3(n_x/(256*8)),    dim3(256), 0, stream>>>(x,    xb,    n_x);
  cvt_bf16<<<dim3(n_wqkv/(256*8)), dim3(256), 0, stream>>>(Wqkv, Wqkvb, n_wqkv);

  gemm_lds<__hip_bfloat16>
    <<<dim3(E3/128, NTOK/128), dim3(256), 0, stream>>>(xb, Wqkvb, qkv, NTOK, E3, DMODEL);

  rope_split<<<dim3(TT/32, BB*HEADS), dim3(256), 0, stream>>>(qkv, Qh, Kh, Vt);

  // xb/Wqkvb dead; Qh/Kh/Vt live. Convert Wproj into dead tail of slot0.
  cvt_bf16<<<dim3(n_wproj/(256*8)), dim3(256), 0, stream>>>(Wproj, Wprojb, n_wproj);

  flash_attn<<<dim3(TT/128, BB*HEADS), dim3(256), 0, stream>>>(Qh, Kh, Vt, attn_out);

  gemm_lds<float>
    <<<dim3(INNER/128, NTOK/128), dim3(256), 0, stream>>>(attn_out, Wprojb, out, NTOK, INNER, DMODEL);
}

// Round 6
// 398.174 us; speedup vs baseline: 1.2134x; 1.0341x over previous
//
#include <hip/hip_runtime.h>
#include <hip/hip_bf16.h>
#include <stdint.h>

typedef __attribute__((ext_vector_type(8))) short short8;
typedef __attribute__((ext_vector_type(4))) float f32x4;

#define HEADS 16
#define HDIM  128
#define BB    2
#define TT    2048
#define DMODEL 2048
#define INNER 2048
#define E3    6144
#define NTOK  (BB*TT)

__device__ inline void store1(__hip_bfloat16* p, float v) { *p = __float2bfloat16(v); }
__device__ inline void store1(float* p, float v)          { *p = v; }

__device__ inline short bfbits(float v) {
  __hip_bfloat16 h = __float2bfloat16(v);
  return *(short*)&h;
}

// async global->LDS, 16 B per lane. LDS dest is wave-uniform base + lane*16.
__device__ inline void gl_lds16(const __hip_bfloat16* g, __hip_bfloat16* l) {
  __builtin_amdgcn_global_load_lds(
      (const __attribute__((address_space(1))) void*)g,
      (__attribute__((address_space(3))) void*)l, 16, 0, 0);
}

// ---------------------------------------------------------------------------
// fp32 -> bf16 pack, 8 elems/thread. n must be a multiple of 8.
// ---------------------------------------------------------------------------
__global__ __launch_bounds__(256)
void cvt_bf16(const float* __restrict__ in, __hip_bfloat16* __restrict__ out, int n)
{
  int i = (blockIdx.x * 256 + threadIdx.x) * 8;
  if (i >= n) return;
  float4 a = *(const float4*)(in + i);
  float4 b = *(const float4*)(in + i + 4);
  short8 r;
  r[0]=bfbits(a.x); r[1]=bfbits(a.y); r[2]=bfbits(a.z); r[3]=bfbits(a.w);
  r[4]=bfbits(b.x); r[5]=bfbits(b.y); r[6]=bfbits(b.z); r[7]=bfbits(b.w);
  *(short8*)(out + i) = r;
}

// ---------------------------------------------------------------------------
// m97-style GEMM (for the output projection): C[M][N] = sum_k A[m][k]*B[n][k].
// ---------------------------------------------------------------------------
template<typename TC>
__global__ __launch_bounds__(256, 2)
void gemm_lds(const __hip_bfloat16* __restrict__ A,
              const __hip_bfloat16* __restrict__ B,
              TC* __restrict__ C,
              int M, int N, int K)
{
  __shared__ __hip_bfloat16 sA[128*32];
  __shared__ __hip_bfloat16 sB[128*32];
  const int tid  = threadIdx.x;
  const int lane = tid & 63;
  const int wv   = tid >> 6;
  const int lm   = lane & 15;
  const int quad = lane >> 4;
  const int wm   = (wv >> 1) * 64;
  const int wn   = (wv & 1) * 64;
  const int bm   = blockIdx.y * 128;
  const int bn   = blockIdx.x * 128;

  f32x4 acc[4][4];
  #pragma unroll
  for (int i=0;i<4;i++)
    #pragma unroll
    for (int j=0;j<4;j++) acc[i][j] = (f32x4){0.f,0.f,0.f,0.f};

  const int srow = wv*32 + (lane >> 2);
  const int scol = (lane & 3) * 8;
  const __hip_bfloat16* gA0 = A + (size_t)(bm + srow)*K + scol;
  const __hip_bfloat16* gA1 = gA0 + (size_t)16*K;
  const __hip_bfloat16* gB0 = B + (size_t)(bn + srow)*K + scol;
  const __hip_bfloat16* gB1 = gB0 + (size_t)16*K;
  __hip_bfloat16* lA0 = sA + wv*1024;
  __hip_bfloat16* lA1 = lA0 + 512;
  __hip_bfloat16* lB0 = sB + wv*1024;
  __hip_bfloat16* lB1 = lB0 + 512;

  for (int k0 = 0; k0 < K; k0 += 32) {
    __syncthreads();
    gl_lds16(gA0, lA0);
    gl_lds16(gA1, lA1);
    gl_lds16(gB0, lB0);
    gl_lds16(gB1, lB1);
    gA0 += 32; gA1 += 32; gB0 += 32; gB1 += 32;
    __syncthreads();
    short8 af[4], bf[4];
    #pragma unroll
    for (int t=0;t<4;t++)
      af[t] = *(const short8*)(sA + (wm + t*16 + lm)*32 + quad*8);
    #pragma unroll
    for (int t=0;t<4;t++)
      bf[t] = *(const short8*)(sB + (wn + t*16 + lm)*32 + quad*8);
    #pragma unroll
    for (int i=0;i<4;i++)
      #pragma unroll
      for (int j=0;j<4;j++)
        acc[i][j] = __builtin_amdgcn_mfma_f32_16x16x32_bf16(af[i], bf[j], acc[i][j], 0,0,0);
  }

  const int row0 = bm + wm + quad*4;
  const int col0 = bn + wn + lm;
  #pragma unroll
  for (int i=0;i<4;i++)
    #pragma unroll
    for (int j=0;j<4;j++)
      #pragma unroll
      for (int r=0;r<4;r++)
        store1(C + (size_t)(row0 + i*16 + r)*N + col0 + j*16, acc[i][j][r]);
}

// ---------------------------------------------------------------------------
// QKV GEMM with fused RoPE + head-split + V-transpose epilogue.
// A = xb [NTOK][DMODEL], B = Wqkvb [E3][DMODEL]. Each 128-col block covers
// exactly one head of one of {Q,K,V}: type = bn>>11, h = (bn>>7)&15.
// Epilogue: tile -> LDS (stride 130), then
//   Q: rope, pre-scale by scale*log2e, write Qh (B,H,T,D)
//   K: rope, write Kh (B,H,T,D)
//   V: transpose, write Vt (B,H,D,T)
// ---------------------------------------------------------------------------
__global__ __launch_bounds__(256, 2)
void gemm_qkv(const __hip_bfloat16* __restrict__ A,
              const __hip_bfloat16* __restrict__ B,
              __hip_bfloat16* __restrict__ Qh,
              __hip_bfloat16* __restrict__ Kh,
              __hip_bfloat16* __restrict__ Vt)
{
  __shared__ __hip_bfloat16 sA[128*32];
  __shared__ __hip_bfloat16 sB[128*32];
  __shared__ __hip_bfloat16 sT[128*130];   // epilogue tile, stride 130
  const int tid  = threadIdx.x;
  const int lane = tid & 63;
  const int wv   = tid >> 6;
  const int lm   = lane & 15;
  const int quad = lane >> 4;
  const int wm   = (wv >> 1) * 64;
  const int wn   = (wv & 1) * 64;
  const int bm   = blockIdx.y * 128;
  const int bn   = blockIdx.x * 128;

  f32x4 acc[4][4];
  #pragma unroll
  for (int i=0;i<4;i++)
    #pragma unroll
    for (int j=0;j<4;j++) acc[i][j] = (f32x4){0.f,0.f,0.f,0.f};

  const int srow = wv*32 + (lane >> 2);
  const int scol = (lane & 3) * 8;
  const __hip_bfloat16* gA0 = A + (size_t)(bm + srow)*DMODEL + scol;
  const __hip_bfloat16* gA1 = gA0 + (size_t)16*DMODEL;
  const __hip_bfloat16* gB0 = B + (size_t)(bn + srow)*DMODEL + scol;
  const __hip_bfloat16* gB1 = gB0 + (size_t)16*DMODEL;
  __hip_bfloat16* lA0 = sA + wv*1024;
  __hip_bfloat16* lA1 = lA0 + 512;
  __hip_bfloat16* lB0 = sB + wv*1024;
  __hip_bfloat16* lB1 = lB0 + 512;

  for (int k0 = 0; k0 < DMODEL; k0 += 32) {
    __syncthreads();
    gl_lds16(gA0, lA0);
    gl_lds16(gA1, lA1);
    gl_lds16(gB0, lB0);
    gl_lds16(gB1, lB1);
    gA0 += 32; gA1 += 32; gB0 += 32; gB1 += 32;
    __syncthreads();
    short8 af[4], bf[4];
    #pragma unroll
    for (int t=0;t<4;t++)
      af[t] = *(const short8*)(sA + (wm + t*16 + lm)*32 + quad*8);
    #pragma unroll
    for (int t=0;t<4;t++)
      bf[t] = *(const short8*)(sB + (wn + t*16 + lm)*32 + quad*8);
    #pragma unroll
    for (int i=0;i<4;i++)
      #pragma unroll
      for (int j=0;j<4;j++)
        acc[i][j] = __builtin_amdgcn_mfma_f32_16x16x32_bf16(af[i], bf[j], acc[i][j], 0,0,0);
  }

  // ---- epilogue: acc -> sT (bf16) ----
  const int trow = wm + quad*4;
  const int tcol = wn + lm;
  #pragma unroll
  for (int i=0;i<4;i++)
    #pragma unroll
    for (int j=0;j<4;j++)
      #pragma unroll
      for (int r=0;r<4;r++)
        sT[(trow + i*16 + r)*130 + tcol + j*16] = __float2bfloat16(acc[i][j][r]);
  __syncthreads();

  const int type = bn >> 11;             // 0=Q 1=K 2=V
  const int h    = (bn >> 7) & 15;
  const int bgl  = bm >> 11;             // batch index (tile never straddles batch)
  const int tl0  = bm & (TT-1);          // local token base
  const size_t bh = (size_t)bgl*HEADS + h;
  const float SCQ = 0.08838834764831845f * 1.4426950408889634f;  // scale*log2(e)

  if (type < 2) {
    __hip_bfloat16* dst = (type == 0) ? Qh : Kh;
    const float mul = (type == 0) ? SCQ : 1.0f;
    #pragma unroll
    for (int p=0;p<4;p++) {
      const int rowl = p*32 + (tid >> 3);
      const int d2b  = (tid & 7) * 8;
      const int t    = tl0 + rowl;
      short8 o1, o2;
      #pragma unroll
      for (int k=0;k<8;k++) {
        const int d2 = d2b + k;
        float v1 = __bfloat162float(sT[rowl*130 + d2]);
        float v2 = __bfloat162float(sT[rowl*130 + d2 + 64]);
        float inv = powf(10000.f, -(float)d2 * (1.f/64.f));
        float ang = (float)t * inv;
        float c = cosf(ang), s = sinf(ang);
        o1[k] = bfbits((v1*c - v2*s) * mul);
        o2[k] = bfbits((v2*c + v1*s) * mul);
      }
      __hip_bfloat16* o = dst + (bh*TT + t)*HDIM + d2b;
      *(short8*)o        = o1;
      *(short8*)(o + 64) = o2;
    }
  } else {
    #pragma unroll
    for (int it2=0; it2<8; ++it2) {
      const int sidx = it2*256 + tid;
      const int d  = sidx >> 4;          // 0..127
      const int tc = (sidx & 15) * 8;    // 0..120
      short8 o;
      #pragma unroll
      for (int k=0;k<8;k++) o[k] = *(const short*)&sT[(tc+k)*130 + d];
      *(short8*)(Vt + (bh*HDIM + d)*TT + tl0 + tc) = o;
    }
  }
}

// ---------------------------------------------------------------------------
// Causal flash attention, paired q-tiles processed sequentially (uniform work,
// no spill). Fixed-max softmax p = 2^(s' - FML2), Q pre-scaled by scale*log2e.
// ---------------------------------------------------------------------------
__global__ __launch_bounds__(256, 3)
void flash_attn(const __hip_bfloat16* __restrict__ Qh,
                const __hip_bfloat16* __restrict__ Kh,
                const __hip_bfloat16* __restrict__ Vt,
                __hip_bfloat16* __restrict__ Out)
{
  const int tid  = threadIdx.x;
  const int lane = tid & 63;
  const int wv   = tid >> 6;
  const int lm   = lane & 15;
  const int quad = lane >> 4;
  const int jA   = blockIdx.x;            // 0..15
  const int bh   = blockIdx.y;
  const int b    = bh >> 4;
  const int h    = bh & 15;

  __shared__ __hip_bfloat16 sK[64*136];    // [kj][d]  stride 136
  __shared__ __hip_bfloat16 sV[128*72];    // [d][kj]  stride 72
  __shared__ __hip_bfloat16 sP[4][16*72];  // per-wave P [qrow][kj]

  const float FML2 = 8.0f * 1.4426950408889634f;  // fixed max, log2 domain

  const int rk0 = tid >> 4;
  const int ck  = (tid & 15) * 8;
  const int dv0 = tid >> 3;
  const int cv  = (tid & 7) * 8;
  const __hip_bfloat16* KpBase = Kh + (size_t)bh*TT*HDIM + (size_t)rk0*HDIM + ck;
  const __hip_bfloat16* VpBase = Vt + (size_t)bh*HDIM*TT + (size_t)dv0*TT + cv;

  #pragma unroll
  for (int pass = 0; pass < 2; ++pass) {
    const int q0 = (pass == 0 ? jA : 31 - jA) * 64;

    short8 aq[4];
    {
      const __hip_bfloat16* qp = Qh + ((size_t)bh*TT + q0 + wv*16 + lm)*HDIM + quad*8;
      #pragma unroll
      for (int kd=0;kd<4;kd++) aq[kd] = *(const short8*)(qp + kd*32);
    }

    float l_p[4] = {0,0,0,0};
    f32x4 acc_o[8];
    #pragma unroll
    for (int i=0;i<8;i++) acc_o[i] = (f32x4){0.f,0.f,0.f,0.f};

    const __hip_bfloat16* Kp = KpBase;
    const __hip_bfloat16* Vp = VpBase;
    short8 pk[4], pv[4];
    #pragma unroll
    for (int it=0;it<4;++it) {
      pk[it] = *(const short8*)(Kp + (size_t)it*16*HDIM);
      pv[it] = *(const short8*)(Vp + (size_t)it*32*TT);
    }
    Kp += (size_t)64*HDIM; Vp += 64;

    for (int kv0 = 0; kv0 <= q0; kv0 += 64) {
      __syncthreads();
      #pragma unroll
      for (int it=0;it<4;++it) {
        *(short8*)(&sK[(it*16 + rk0)*136 + ck]) = pk[it];
        *(short8*)(&sV[(it*32 + dv0)*72 + cv])  = pv[it];
      }
      if (kv0 + 64 <= q0) {
        #pragma unroll
        for (int it=0;it<4;++it) {
          pk[it] = *(const short8*)(Kp + (size_t)it*16*HDIM);
          pv[it] = *(const short8*)(Vp + (size_t)it*32*TT);
        }
        Kp += (size_t)64*HDIM; Vp += 64;
      }
      __syncthreads();

      f32x4 accs[4];
      #pragma unroll
      for (int nt=0;nt<4;nt++) accs[nt] = (f32x4){0.f,0.f,0.f,0.f};
      #pragma unroll
      for (int kd=0;kd<4;kd++)
        #pragma unroll
        for (int nt=0;nt<4;nt++) {
          short8 bk = *(const short8*)(&sK[(nt*16 + lm)*136 + kd*32 + quad*8]);
          accs[nt] = __builtin_amdgcn_mfma_f32_16x16x32_bf16(aq[kd], bk, accs[nt], 0,0,0);
        }

      const int rowb = q0 + wv*16 + quad*4;
      const bool diag = (kv0 == q0);
      #pragma unroll
      for (int nt=0;nt<4;nt++)
        #pragma unroll
        for (int r=0;r<4;r++) {
          float p = exp2f(accs[nt][r] - FML2);
          if (diag && (kv0 + nt*16 + lm > rowb + r)) p = 0.f;
          l_p[r] += p;
          sP[wv][(quad*4 + r)*72 + nt*16 + lm] = __float2bfloat16(p);
        }

      #pragma unroll
      for (int kd2=0;kd2<2;kd2++) {
        short8 ap = *(const short8*)(&sP[wv][lm*72 + kd2*32 + quad*8]);
        #pragma unroll
        for (int nt2=0;nt2<8;nt2++) {
          short8 bvv = *(const short8*)(&sV[(nt2*16 + lm)*72 + kd2*32 + quad*8]);
          acc_o[nt2] = __builtin_amdgcn_mfma_f32_16x16x32_bf16(ap, bvv, acc_o[nt2], 0,0,0);
        }
      }
    }

    #pragma unroll
    for (int off=1; off<16; off<<=1)
      #pragma unroll
      for (int r=0;r<4;r++) l_p[r] += __shfl_xor(l_p[r], off);
    #pragma unroll
    for (int r=0;r<4;r++) l_p[r] = 1.f / l_p[r];

    #pragma unroll
    for (int nt2=0;nt2<8;nt2++)
      #pragma unroll
      for (int r=0;r<4;r++) {
        int t = q0 + wv*16 + quad*4 + r;
        Out[((size_t)b*TT + t)*INNER + (size_t)h*HDIM + nt2*16 + lm] =
          __float2bfloat16(acc_o[nt2][r] * l_p[r]);
      }
  }
}

// ---------------------------------------------------------------------------
extern "C" void kernel_launch(void* const* d_in, const int* in_sizes, int n_in,
                              void* d_out, int out_size, void* d_ws, size_t ws_size,
                              hipStream_t stream)
{
  (void)in_sizes; (void)n_in; (void)out_size; (void)ws_size;
  const float* x     = (const float*)d_in[0];
  const float* Wqkv  = (const float*)d_in[1];
  const float* Wproj = (const float*)d_in[2];
  float* out = (float*)d_out;

  // Workspace (92.3 MB):
  //  [0, 16.78): xb -> attn_out (xb dead after gemm_qkv)
  //  [16.78, 41.94): Wqkvb -> Wprojb overlay (dead after gemm_qkv)
  //  [41.94, 58.72): Qh   [58.72, 75.50): Kh   [75.50, 92.27): Vt
  char* ws = (char*)d_ws;
  __hip_bfloat16* xb       = (__hip_bfloat16*)ws;
  __hip_bfloat16* attn_out = xb;
  char* p1 = ws + (size_t)NTOK*DMODEL*2;
  __hip_bfloat16* Wqkvb  = (__hip_bfloat16*)p1;
  __hip_bfloat16* Wprojb = (__hip_bfloat16*)p1;
  char* p2 = p1 + (size_t)E3*DMODEL*2;
  const size_t hsz = (size_t)BB*HEADS*TT*HDIM*2;
  __hip_bfloat16* Qh = (__hip_bfloat16*)p2;
  __hip_bfloat16* Kh = (__hip_bfloat16*)(p2 + hsz);
  __hip_bfloat16* Vt = (__hip_bfloat16*)(p2 + 2*hsz);

  const int n_x = NTOK*DMODEL, n_wqkv = E3*DMODEL, n_wproj = DMODEL*INNER;
  cvt_bf16<<<dim3(n_x/(256*8)),    dim3(256), 0, stream>>>(x,    xb,    n_x);
  cvt_bf16<<<dim3(n_wqkv/(256*8)), dim3(256), 0, stream>>>(Wqkv, Wqkvb, n_wqkv);

  gemm_qkv<<<dim3(E3/128, NTOK/128), dim3(256), 0, stream>>>(xb, Wqkvb, Qh, Kh, Vt);

  // Wqkvb dead; overlay Wprojb in its slot.
  cvt_bf16<<<dim3(n_wproj/(256*8)), dim3(256), 0, stream>>>(Wproj, Wprojb, n_wproj);

  flash_attn<<<dim3(TT/128, BB*HEADS), dim3(256), 0, stream>>>(Qh, Kh, Vt, attn_out);

  gemm_lds<float>
    <<<dim3(INNER/128, NTOK/128), dim3(256), 0, stream>>>(attn_out, Wprojb, out, NTOK, INNER, DMODEL);
}

// Round 7
// 384.078 us; speedup vs baseline: 1.2579x; 1.0367x over previous
//
#include <hip/hip_runtime.h>
#include <hip/hip_bf16.h>
#include <stdint.h>

typedef __attribute__((ext_vector_type(8))) short short8;
typedef __attribute__((ext_vector_type(4))) float f32x4;

#define HEADS 16
#define HDIM  128
#define BB    2
#define TT    2048
#define DMODEL 2048
#define INNER 2048
#define E3    6144
#define NTOK  (BB*TT)

__device__ inline void store1(__hip_bfloat16* p, float v) { *p = __float2bfloat16(v); }
__device__ inline void store1(float* p, float v)          { *p = v; }

__device__ inline short bfbits(float v) {
  __hip_bfloat16 h = __float2bfloat16(v);
  return *(short*)&h;
}

// async global->LDS, 16 B per lane. LDS dest is wave-uniform base + lane*16.
__device__ inline void gl_lds16(const __hip_bfloat16* g, __hip_bfloat16* l) {
  __builtin_amdgcn_global_load_lds(
      (const __attribute__((address_space(1))) void*)g,
      (__attribute__((address_space(3))) void*)l, 16, 0, 0);
}

__device__ inline void cvt8(const float* in, __hip_bfloat16* out, int i) {
  float4 a = *(const float4*)(in + i);
  float4 b = *(const float4*)(in + i + 4);
  short8 r;
  r[0]=bfbits(a.x); r[1]=bfbits(a.y); r[2]=bfbits(a.z); r[3]=bfbits(a.w);
  r[4]=bfbits(b.x); r[5]=bfbits(b.y); r[6]=bfbits(b.z); r[7]=bfbits(b.w);
  *(short8*)(out + i) = r;
}

// ---------------------------------------------------------------------------
// prep: cvt x->bf16 (4096 blocks), cvt Wqkv->bf16 (6144 blocks),
//       fill rope table cos/sin (512 blocks). One launch.
// ---------------------------------------------------------------------------
#define NBX   (NTOK*DMODEL/2048)    // 4096
#define NBW   (E3*DMODEL/2048)      // 6144
#define NBT   (TT*64/256)           // 512
__global__ __launch_bounds__(256)
void prep(const float* __restrict__ x, const float* __restrict__ Wqkv,
          __hip_bfloat16* __restrict__ xb, __hip_bfloat16* __restrict__ Wqkvb,
          float2* __restrict__ tab)
{
  const int tid = threadIdx.x;
  int blk = blockIdx.x;
  if (blk < NBX) {
    cvt8(x, xb, (blk*256 + tid)*8);
  } else if (blk < NBX + NBW) {
    cvt8(Wqkv, Wqkvb, ((blk-NBX)*256 + tid)*8);
  } else {
    int idx = (blk - NBX - NBW)*256 + tid;   // 0..131071
    int t  = idx >> 6;
    int d2 = idx & 63;
    float inv = powf(10000.f, -(float)d2 * (1.f/64.f));
    float ang = (float)t * inv;
    tab[idx] = make_float2(cosf(ang), sinf(ang));
  }
}

// ---------------------------------------------------------------------------
// fp32 -> bf16 pack, 8 elems/thread (for Wproj, after gemm_qkv frees its slot)
// ---------------------------------------------------------------------------
__global__ __launch_bounds__(256)
void cvt_bf16(const float* __restrict__ in, __hip_bfloat16* __restrict__ out, int n)
{
  int i = (blockIdx.x * 256 + threadIdx.x) * 8;
  if (i >= n) return;
  cvt8(in, out, i);
}

// ---------------------------------------------------------------------------
// m97-style GEMM (output projection): C[M][N] = sum_k A[m][k]*B[n][k].
// ---------------------------------------------------------------------------
template<typename TC>
__global__ __launch_bounds__(256, 2)
void gemm_lds(const __hip_bfloat16* __restrict__ A,
              const __hip_bfloat16* __restrict__ B,
              TC* __restrict__ C,
              int M, int N, int K)
{
  __shared__ __hip_bfloat16 sA[128*32];
  __shared__ __hip_bfloat16 sB[128*32];
  const int tid  = threadIdx.x;
  const int lane = tid & 63;
  const int wv   = tid >> 6;
  const int lm   = lane & 15;
  const int quad = lane >> 4;
  const int wm   = (wv >> 1) * 64;
  const int wn   = (wv & 1) * 64;
  const int bm   = blockIdx.y * 128;
  const int bn   = blockIdx.x * 128;

  f32x4 acc[4][4];
  #pragma unroll
  for (int i=0;i<4;i++)
    #pragma unroll
    for (int j=0;j<4;j++) acc[i][j] = (f32x4){0.f,0.f,0.f,0.f};

  const int srow = wv*32 + (lane >> 2);
  const int scol = (lane & 3) * 8;
  const __hip_bfloat16* gA0 = A + (size_t)(bm + srow)*K + scol;
  const __hip_bfloat16* gA1 = gA0 + (size_t)16*K;
  const __hip_bfloat16* gB0 = B + (size_t)(bn + srow)*K + scol;
  const __hip_bfloat16* gB1 = gB0 + (size_t)16*K;
  __hip_bfloat16* lA0 = sA + wv*1024;
  __hip_bfloat16* lA1 = lA0 + 512;
  __hip_bfloat16* lB0 = sB + wv*1024;
  __hip_bfloat16* lB1 = lB0 + 512;

  for (int k0 = 0; k0 < K; k0 += 32) {
    __syncthreads();
    gl_lds16(gA0, lA0);
    gl_lds16(gA1, lA1);
    gl_lds16(gB0, lB0);
    gl_lds16(gB1, lB1);
    gA0 += 32; gA1 += 32; gB0 += 32; gB1 += 32;
    __syncthreads();
    short8 af[4], bf[4];
    #pragma unroll
    for (int t=0;t<4;t++)
      af[t] = *(const short8*)(sA + (wm + t*16 + lm)*32 + quad*8);
    #pragma unroll
    for (int t=0;t<4;t++)
      bf[t] = *(const short8*)(sB + (wn + t*16 + lm)*32 + quad*8);
    #pragma unroll
    for (int i=0;i<4;i++)
      #pragma unroll
      for (int j=0;j<4;j++)
        acc[i][j] = __builtin_amdgcn_mfma_f32_16x16x32_bf16(af[i], bf[j], acc[i][j], 0,0,0);
  }

  const int row0 = bm + wm + quad*4;
  const int col0 = bn + wn + lm;
  #pragma unroll
  for (int i=0;i<4;i++)
    #pragma unroll
    for (int j=0;j<4;j++)
      #pragma unroll
      for (int r=0;r<4;r++)
        store1(C + (size_t)(row0 + i*16 + r)*N + col0 + j*16, acc[i][j][r]);
}

// ---------------------------------------------------------------------------
// QKV GEMM with fused RoPE (table-based) + head-split + V-transpose epilogue.
// sT overlaps sA/sB (union) -> LDS 33.3 KB -> 4 blocks/CU.
// ---------------------------------------------------------------------------
__global__ __launch_bounds__(256, 2)
void gemm_qkv(const __hip_bfloat16* __restrict__ A,
              const __hip_bfloat16* __restrict__ B,
              const float2* __restrict__ tab,
              __hip_bfloat16* __restrict__ Qh,
              __hip_bfloat16* __restrict__ Kh,
              __hip_bfloat16* __restrict__ Vt)
{
  __shared__ __hip_bfloat16 smem[128*130];       // sT; sA/sB overlap its head
  __hip_bfloat16* sA = smem;                     // [0, 8192)
  __hip_bfloat16* sB = smem + 128*32;            // [8192, 16384)
  __hip_bfloat16* sT = smem;                     // epilogue tile, stride 130
  const int tid  = threadIdx.x;
  const int lane = tid & 63;
  const int wv   = tid >> 6;
  const int lm   = lane & 15;
  const int quad = lane >> 4;
  const int wm   = (wv >> 1) * 64;
  const int wn   = (wv & 1) * 64;
  const int bm   = blockIdx.y * 128;
  const int bn   = blockIdx.x * 128;

  f32x4 acc[4][4];
  #pragma unroll
  for (int i=0;i<4;i++)
    #pragma unroll
    for (int j=0;j<4;j++) acc[i][j] = (f32x4){0.f,0.f,0.f,0.f};

  const int srow = wv*32 + (lane >> 2);
  const int scol = (lane & 3) * 8;
  const __hip_bfloat16* gA0 = A + (size_t)(bm + srow)*DMODEL + scol;
  const __hip_bfloat16* gA1 = gA0 + (size_t)16*DMODEL;
  const __hip_bfloat16* gB0 = B + (size_t)(bn + srow)*DMODEL + scol;
  const __hip_bfloat16* gB1 = gB0 + (size_t)16*DMODEL;
  __hip_bfloat16* lA0 = sA + wv*1024;
  __hip_bfloat16* lA1 = lA0 + 512;
  __hip_bfloat16* lB0 = sB + wv*1024;
  __hip_bfloat16* lB1 = lB0 + 512;

  for (int k0 = 0; k0 < DMODEL; k0 += 32) {
    __syncthreads();
    gl_lds16(gA0, lA0);
    gl_lds16(gA1, lA1);
    gl_lds16(gB0, lB0);
    gl_lds16(gB1, lB1);
    gA0 += 32; gA1 += 32; gB0 += 32; gB1 += 32;
    __syncthreads();
    short8 af[4], bf[4];
    #pragma unroll
    for (int t=0;t<4;t++)
      af[t] = *(const short8*)(sA + (wm + t*16 + lm)*32 + quad*8);
    #pragma unroll
    for (int t=0;t<4;t++)
      bf[t] = *(const short8*)(sB + (wn + t*16 + lm)*32 + quad*8);
    #pragma unroll
    for (int i=0;i<4;i++)
      #pragma unroll
      for (int j=0;j<4;j++)
        acc[i][j] = __builtin_amdgcn_mfma_f32_16x16x32_bf16(af[i], bf[j], acc[i][j], 0,0,0);
  }

  __syncthreads();   // retire all fragment reads before sT overwrites sA/sB

  // ---- epilogue: acc -> sT (bf16) ----
  const int trow = wm + quad*4;
  const int tcol = wn + lm;
  #pragma unroll
  for (int i=0;i<4;i++)
    #pragma unroll
    for (int j=0;j<4;j++)
      #pragma unroll
      for (int r=0;r<4;r++)
        sT[(trow + i*16 + r)*130 + tcol + j*16] = __float2bfloat16(acc[i][j][r]);
  __syncthreads();

  const int type = bn >> 11;             // 0=Q 1=K 2=V
  const int h    = (bn >> 7) & 15;
  const int bgl  = bm >> 11;             // batch index (tile never straddles batch)
  const int tl0  = bm & (TT-1);          // local token base
  const size_t bh = (size_t)bgl*HEADS + h;
  const float SCQ = 0.08838834764831845f * 1.4426950408889634f;  // scale*log2(e)

  if (type < 2) {
    __hip_bfloat16* dst = (type == 0) ? Qh : Kh;
    const float mul = (type == 0) ? SCQ : 1.0f;
    #pragma unroll
    for (int p=0;p<4;p++) {
      const int rowl = p*32 + (tid >> 3);
      const int d2b  = (tid & 7) * 8;
      const int t    = tl0 + rowl;
      const float2* tp = tab + (size_t)t*64 + d2b;
      short8 o1, o2;
      #pragma unroll
      for (int k=0;k<8;k++) {
        float2 cs = tp[k];
        float v1 = __bfloat162float(sT[rowl*130 + d2b + k]);
        float v2 = __bfloat162float(sT[rowl*130 + d2b + k + 64]);
        o1[k] = bfbits((v1*cs.x - v2*cs.y) * mul);
        o2[k] = bfbits((v2*cs.x + v1*cs.y) * mul);
      }
      __hip_bfloat16* o = dst + (bh*TT + t)*HDIM + d2b;
      *(short8*)o        = o1;
      *(short8*)(o + 64) = o2;
    }
  } else {
    #pragma unroll
    for (int it2=0; it2<8; ++it2) {
      const int sidx = it2*256 + tid;
      const int d  = sidx >> 4;          // 0..127
      const int tc = (sidx & 15) * 8;    // 0..120
      short8 o;
      #pragma unroll
      for (int k=0;k<8;k++) o[k] = *(const short*)&sT[(tc+k)*130 + d];
      *(short8*)(Vt + (bh*HDIM + d)*TT + tl0 + tc) = o;
    }
  }
}

// ---------------------------------------------------------------------------
// Causal flash attention, paired q-tiles processed sequentially (uniform work,
// no spill). Fixed-max softmax p = 2^(s' - FML2), Q pre-scaled by scale*log2e.
// ---------------------------------------------------------------------------
__global__ __launch_bounds__(256, 3)
void flash_attn(const __hip_bfloat16* __restrict__ Qh,
                const __hip_bfloat16* __restrict__ Kh,
                const __hip_bfloat16* __restrict__ Vt,
                __hip_bfloat16* __restrict__ Out)
{
  const int tid  = threadIdx.x;
  const int lane = tid & 63;
  const int wv   = tid >> 6;
  const int lm   = lane & 15;
  const int quad = lane >> 4;
  const int jA   = blockIdx.x;            // 0..15
  const int bh   = blockIdx.y;
  const int b    = bh >> 4;
  const int h    = bh & 15;

  __shared__ __hip_bfloat16 sK[64*136];
  __shared__ __hip_bfloat16 sV[128*72];
  __shared__ __hip_bfloat16 sP[4][16*72];

  const float FML2 = 8.0f * 1.4426950408889634f;

  const int rk0 = tid >> 4;
  const int ck  = (tid & 15) * 8;
  const int dv0 = tid >> 3;
  const int cv  = (tid & 7) * 8;
  const __hip_bfloat16* KpBase = Kh + (size_t)bh*TT*HDIM + (size_t)rk0*HDIM + ck;
  const __hip_bfloat16* VpBase = Vt + (size_t)bh*HDIM*TT + (size_t)dv0*TT + cv;

  #pragma unroll
  for (int pass = 0; pass < 2; ++pass) {
    const int q0 = (pass == 0 ? jA : 31 - jA) * 64;

    short8 aq[4];
    {
      const __hip_bfloat16* qp = Qh + ((size_t)bh*TT + q0 + wv*16 + lm)*HDIM + quad*8;
      #pragma unroll
      for (int kd=0;kd<4;kd++) aq[kd] = *(const short8*)(qp + kd*32);
    }

    float l_p[4] = {0,0,0,0};
    f32x4 acc_o[8];
    #pragma unroll
    for (int i=0;i<8;i++) acc_o[i] = (f32x4){0.f,0.f,0.f,0.f};

    const __hip_bfloat16* Kp = KpBase;
    const __hip_bfloat16* Vp = VpBase;
    short8 pk[4], pv[4];
    #pragma unroll
    for (int it=0;it<4;++it) {
      pk[it] = *(const short8*)(Kp + (size_t)it*16*HDIM);
      pv[it] = *(const short8*)(Vp + (size_t)it*32*TT);
    }
    Kp += (size_t)64*HDIM; Vp += 64;

    for (int kv0 = 0; kv0 <= q0; kv0 += 64) {
      __syncthreads();
      #pragma unroll
      for (int it=0;it<4;++it) {
        *(short8*)(&sK[(it*16 + rk0)*136 + ck]) = pk[it];
        *(short8*)(&sV[(it*32 + dv0)*72 + cv])  = pv[it];
      }
      if (kv0 + 64 <= q0) {
        #pragma unroll
        for (int it=0;it<4;++it) {
          pk[it] = *(const short8*)(Kp + (size_t)it*16*HDIM);
          pv[it] = *(const short8*)(Vp + (size_t)it*32*TT);
        }
        Kp += (size_t)64*HDIM; Vp += 64;
      }
      __syncthreads();

      f32x4 accs[4];
      #pragma unroll
      for (int nt=0;nt<4;nt++) accs[nt] = (f32x4){0.f,0.f,0.f,0.f};
      #pragma unroll
      for (int kd=0;kd<4;kd++)
        #pragma unroll
        for (int nt=0;nt<4;nt++) {
          short8 bk = *(const short8*)(&sK[(nt*16 + lm)*136 + kd*32 + quad*8]);
          accs[nt] = __builtin_amdgcn_mfma_f32_16x16x32_bf16(aq[kd], bk, accs[nt], 0,0,0);
        }

      const int rowb = q0 + wv*16 + quad*4;
      const bool diag = (kv0 == q0);
      #pragma unroll
      for (int nt=0;nt<4;nt++)
        #pragma unroll
        for (int r=0;r<4;r++) {
          float p = exp2f(accs[nt][r] - FML2);
          if (diag && (kv0 + nt*16 + lm > rowb + r)) p = 0.f;
          l_p[r] += p;
          sP[wv][(quad*4 + r)*72 + nt*16 + lm] = __float2bfloat16(p);
        }

      #pragma unroll
      for (int kd2=0;kd2<2;kd2++) {
        short8 ap = *(const short8*)(&sP[wv][lm*72 + kd2*32 + quad*8]);
        #pragma unroll
        for (int nt2=0;nt2<8;nt2++) {
          short8 bvv = *(const short8*)(&sV[(nt2*16 + lm)*72 + kd2*32 + quad*8]);
          acc_o[nt2] = __builtin_amdgcn_mfma_f32_16x16x32_bf16(ap, bvv, acc_o[nt2], 0,0,0);
        }
      }
    }

    #pragma unroll
    for (int off=1; off<16; off<<=1)
      #pragma unroll
      for (int r=0;r<4;r++) l_p[r] += __shfl_xor(l_p[r], off);
    #pragma unroll
    for (int r=0;r<4;r++) l_p[r] = 1.f / l_p[r];

    #pragma unroll
    for (int nt2=0;nt2<8;nt2++)
      #pragma unroll
      for (int r=0;r<4;r++) {
        int t = q0 + wv*16 + quad*4 + r;
        Out[((size_t)b*TT + t)*INNER + (size_t)h*HDIM + nt2*16 + lm] =
          __float2bfloat16(acc_o[nt2][r] * l_p[r]);
      }
  }
}

// ---------------------------------------------------------------------------
extern "C" void kernel_launch(void* const* d_in, const int* in_sizes, int n_in,
                              void* d_out, int out_size, void* d_ws, size_t ws_size,
                              hipStream_t stream)
{
  (void)in_sizes; (void)n_in; (void)out_size; (void)ws_size;
  const float* x     = (const float*)d_in[0];
  const float* Wqkv  = (const float*)d_in[1];
  const float* Wproj = (const float*)d_in[2];
  float* out = (float*)d_out;

  // Workspace (100.66 MB, R3-proven size):
  //  [0, 16.78): xb -> attn_out (xb dead after gemm_qkv)
  //  [16.78, 41.94): Wqkvb -> Wprojb overlay (Wqkvb dead after gemm_qkv)
  //  [41.94, 50.33): rope table (1 MB used; dead after gemm_qkv)
  //  [50.33, 67.11): Qh  [67.11, 83.89): Kh  [83.89, 100.66): Vt
  char* ws = (char*)d_ws;
  __hip_bfloat16* xb       = (__hip_bfloat16*)ws;
  __hip_bfloat16* attn_out = xb;
  char* p1 = ws + (size_t)NTOK*DMODEL*2;
  __hip_bfloat16* Wqkvb  = (__hip_bfloat16*)p1;
  __hip_bfloat16* Wprojb = (__hip_bfloat16*)p1;
  char* p2 = p1 + (size_t)E3*DMODEL*2;
  float2* ropeTab = (float2*)p2;
  char* p3 = p2 + (size_t)DMODEL*INNER*2;   // 8.39 MB slot (table uses 1 MB)
  const size_t hsz = (size_t)BB*HEADS*TT*HDIM*2;
  __hip_bfloat16* Qh = (__hip_bfloat16*)p3;
  __hip_bfloat16* Kh = (__hip_bfloat16*)(p3 + hsz);
  __hip_bfloat16* Vt = (__hip_bfloat16*)(p3 + 2*hsz);

  prep<<<dim3(NBX + NBW + NBT), dim3(256), 0, stream>>>(x, Wqkv, xb, Wqkvb, ropeTab);

  gemm_qkv<<<dim3(E3/128, NTOK/128), dim3(256), 0, stream>>>(xb, Wqkvb, ropeTab, Qh, Kh, Vt);

  // Wqkvb + table dead; overlay Wprojb.
  cvt_bf16<<<dim3(DMODEL*INNER/2048), dim3(256), 0, stream>>>(Wproj, Wprojb, DMODEL*INNER);

  flash_attn<<<dim3(TT/128, BB*HEADS), dim3(256), 0, stream>>>(Qh, Kh, Vt, attn_out);

  gemm_lds<float>
    <<<dim3(INNER/128, NTOK/128), dim3(256), 0, stream>>>(attn_out, Wprojb, out, NTOK, INNER, DMODEL);
}